// Round 2
// baseline (98.021 us; speedup 1.0000x reference)
//
#include <hip/hip_runtime.h>
#include <hip/hip_bf16.h>

// Problem constants (from setup_inputs): features [16, 512, 56, 56] f32, k=3 -> d=1
#define BB 16
#define CC 512
#define HH 56
#define WW 56
#define HW (HH * WW)
#define NPIX (BB * HW)

__device__ __forceinline__ float shfl64(float v, int srcLane) {
    return __shfl(v, srcLane, 64);
}

// Thread layout: lane = rl*16 + q (rl = row-in-wave 0..3, q = x-block 0..13 active).
// Each thread computes 4 consecutive x (x0 = 4q) for one row y, looping channels.
// Verified math (round 1, absmax 2e-3 < 9e-3): masks & 1/9 cancel in cosine;
//   V  = mym*g(y-1) + g(y) + myp*g(y+1)
//   w3 = mym*g(y)   + g(cl(y+1)) + myp*g(cl(y+2))
//   w4 = mym*g(cl(y-2)) + g(cl(y-1)) + myp*g(y)
//   f1(x) = mxm*V(cl(x-2)) + V(cl(x-1)) + mxp*V(x)
//   f2(x) = mxm*V(x) + V(cl(x+1)) + mxp*V(cl(x+2))
//   f3(x) = mxm*w3(cl(x-1)) + w3(x) + mxp*w3(cl(x+1))
//   f4(x) = mxm*w4(cl(x-1)) + w4(x) + mxp*w4(cl(x+1))
template <int CCHUNK, bool WRITE_OUT>
__global__ __launch_bounds__(256) void ComputeTotalSim_84267258347855_kernel(
    const float* __restrict__ feat, float* __restrict__ acc, float* __restrict__ out) {
    const int wave = threadIdx.x >> 6;
    const int lane = threadIdx.x & 63;
    const int rl = lane >> 4;
    const int q = lane & 15;
    const int y = blockIdx.y * 16 + wave * 4 + rl;
    if (y >= HH) return;  // uniform per wave (all 4 rl share validity by strip)

    const int b = blockIdx.z;
    const int x0 = q * 4;
    const int x0c = (x0 <= WW - 4) ? x0 : (WW - 4);  // load-safe for idle lanes q>=14

    const float mym = (y >= 1) ? 1.f : 0.f;
    const float myp = (y <= HH - 2) ? 1.f : 0.f;
    const float mxm[4] = {(q == 0) ? 0.f : 1.f, 1.f, 1.f, 1.f};   // (x>=1)
    const float mxp[4] = {1.f, 1.f, 1.f, (q == 13) ? 0.f : 1.f};  // (x<=54)

    const int ry0 = (y - 2 < 0) ? 0 : y - 2;
    const int ry1 = (y - 1 < 0) ? 0 : y - 1;
    const int ry2 = y;
    const int ry3 = (y + 1 > HH - 1) ? HH - 1 : y + 1;
    const int ry4 = (y + 2 > HH - 1) ? HH - 1 : y + 2;
    const int o0 = ry0 * WW + x0c, o1 = ry1 * WW + x0c, o2 = ry2 * WW + x0c,
              o3 = ry3 * WW + x0c, o4 = ry4 * WW + x0c;

    const float* p = feat + ((size_t)b * CC + (size_t)blockIdx.x * CCHUNK) * HW;

    float s12h[4] = {0, 0, 0, 0}, s11[4] = {0, 0, 0, 0}, s22[4] = {0, 0, 0, 0};
    float s12v[4] = {0, 0, 0, 0}, s33[4] = {0, 0, 0, 0}, s44[4] = {0, 0, 0, 0};

#pragma unroll 2
    for (int c = 0; c < CCHUNK; ++c, p += HW) {
        const float4 r0 = *(const float4*)(p + o0);
        const float4 r1 = *(const float4*)(p + o1);
        const float4 r2 = *(const float4*)(p + o2);
        const float4 r3 = *(const float4*)(p + o3);
        const float4 r4 = *(const float4*)(p + o4);

        float4 V, w3, w4;
        V.x = fmaf(mym, r1.x, fmaf(myp, r3.x, r2.x));
        V.y = fmaf(mym, r1.y, fmaf(myp, r3.y, r2.y));
        V.z = fmaf(mym, r1.z, fmaf(myp, r3.z, r2.z));
        V.w = fmaf(mym, r1.w, fmaf(myp, r3.w, r2.w));
        w3.x = fmaf(mym, r2.x, fmaf(myp, r4.x, r3.x));
        w3.y = fmaf(mym, r2.y, fmaf(myp, r4.y, r3.y));
        w3.z = fmaf(mym, r2.z, fmaf(myp, r4.z, r3.z));
        w3.w = fmaf(mym, r2.w, fmaf(myp, r4.w, r3.w));
        w4.x = fmaf(mym, r0.x, fmaf(myp, r2.x, r1.x));
        w4.y = fmaf(mym, r0.y, fmaf(myp, r2.y, r1.y));
        w4.z = fmaf(mym, r0.z, fmaf(myp, r2.z, r1.z));
        w4.w = fmaf(mym, r0.w, fmaf(myp, r2.w, r1.w));

        // halo from neighbor lanes (8 shuffles per 4 pixels)
        float Vm2 = shfl64(V.z, lane - 1), Vm1 = shfl64(V.w, lane - 1);
        float Vp4 = shfl64(V.x, lane + 1), Vp5 = shfl64(V.y, lane + 1);
        float w3m = shfl64(w3.w, lane - 1), w3p = shfl64(w3.x, lane + 1);
        float w4m = shfl64(w4.w, lane - 1), w4p = shfl64(w4.x, lane + 1);
        if (q == 0) { Vm2 = V.x; Vm1 = V.x; w3m = w3.x; w4m = w4.x; }     // clamp left
        if (q == 13) { Vp4 = V.w; Vp5 = V.w; w3p = w3.w; w4p = w4.w; }    // clamp right

        const float Ve[8] = {Vm2, Vm1, V.x, V.y, V.z, V.w, Vp4, Vp5};
        const float W3[6] = {w3m, w3.x, w3.y, w3.z, w3.w, w3p};
        const float W4[6] = {w4m, w4.x, w4.y, w4.z, w4.w, w4p};

#pragma unroll
        for (int i = 0; i < 4; ++i) {
            const float f1 = fmaf(mxm[i], Ve[i],     fmaf(mxp[i], Ve[i + 2], Ve[i + 1]));
            const float f2 = fmaf(mxm[i], Ve[i + 2], fmaf(mxp[i], Ve[i + 4], Ve[i + 3]));
            const float f3 = fmaf(mxm[i], W3[i],     fmaf(mxp[i], W3[i + 2], W3[i + 1]));
            const float f4 = fmaf(mxm[i], W4[i],     fmaf(mxp[i], W4[i + 2], W4[i + 1]));
            s12h[i] = fmaf(f1, f2, s12h[i]);
            s11[i]  = fmaf(f1, f1, s11[i]);
            s22[i]  = fmaf(f2, f2, s22[i]);
            s12v[i] = fmaf(f3, f4, s12v[i]);
            s33[i]  = fmaf(f3, f3, s33[i]);
            s44[i]  = fmaf(f4, f4, s44[i]);
        }
    }

    if (q < 14) {
        const int pix = b * HW + y * WW + x0;
        if (WRITE_OUT) {
#pragma unroll
            for (int i = 0; i < 4; ++i) {
                const double num =
                    0.5 * ((double)s12h[i] / sqrt((double)s11[i] * (double)s22[i]) +
                           (double)s12v[i] / sqrt((double)s33[i] * (double)s44[i]));
                out[pix + i] = (float)num;
            }
        } else {
#pragma unroll
            for (int i = 0; i < 4; ++i) {
                atomicAdd(&acc[0 * NPIX + pix + i], s12h[i]);
                atomicAdd(&acc[1 * NPIX + pix + i], s11[i]);
                atomicAdd(&acc[2 * NPIX + pix + i], s22[i]);
                atomicAdd(&acc[3 * NPIX + pix + i], s12v[i]);
                atomicAdd(&acc[4 * NPIX + pix + i], s33[i]);
                atomicAdd(&acc[5 * NPIX + pix + i], s44[i]);
            }
        }
    }
}

__global__ void ComputeTotalSim_finalize(const float* __restrict__ acc,
                                         float* __restrict__ out) {
    const int i = blockIdx.x * blockDim.x + threadIdx.x;
    if (i < NPIX) {
        const double s12h = acc[i],            s11 = acc[NPIX + i],     s22 = acc[2 * NPIX + i];
        const double s12v = acc[3 * NPIX + i], s33 = acc[4 * NPIX + i], s44 = acc[5 * NPIX + i];
        out[i] = (float)(0.5 * (s12h / sqrt(s11 * s22) + s12v / sqrt(s33 * s44)));
    }
}

extern "C" void kernel_launch(void* const* d_in, const int* in_sizes, int n_in,
                              void* d_out, int out_size, void* d_ws, size_t ws_size,
                              hipStream_t stream) {
    const float* feat = (const float*)d_in[0];
    float* out = (float*)d_out;

    const size_t need = 6ull * NPIX * sizeof(float);
    if (ws_size >= need) {
        // Two-phase: channel-chunked partial sums via atomics, then finalize.
        hipMemsetAsync(d_ws, 0, need, stream);
        dim3 grid(CC / 32, 4, BB);  // 16 c-chunks x 4 y-strips(16 rows) x 16 batches
        ComputeTotalSim_84267258347855_kernel<32, false>
            <<<grid, 256, 0, stream>>>(feat, (float*)d_ws, out);
        ComputeTotalSim_finalize<<<(NPIX + 255) / 256, 256, 0, stream>>>(
            (const float*)d_ws, out);
    } else {
        // Fallback: one block does all channels, writes output directly.
        dim3 grid(1, 4, BB);
        ComputeTotalSim_84267258347855_kernel<CC, true>
            <<<grid, 256, 0, stream>>>(feat, nullptr, out);
    }
}

// Round 3
// 86.611 us; speedup vs baseline: 1.1317x; 1.1317x over previous
//
#include <hip/hip_runtime.h>
#include <hip/hip_bf16.h>

// Problem constants (from setup_inputs): features [16, 512, 56, 56] f32, k=3 -> d=1
#define BB 16
#define CC 512
#define HH 56
#define WW 56
#define HW (HH * WW)
#define NPIX (BB * HW)
#define NVALS (6 * 4 * WW)  // 6 planes x 4 rows x 56 px = 1344 per block

__device__ __forceinline__ float shfl64(float v, int srcLane) {
    return __shfl(v, srcLane, 64);
}

// Wave layout: lane = rl*16 + q; rl = row 0..3 within the 4-row strip, q = x-quad
// (q<14 active, x0 = 4q, float4 per thread). Each of the 4 waves in a block
// handles a DIFFERENT 16-channel chunk of the SAME 224 pixels; block reduces in
// LDS, then does contiguous-address global atomics (8 partials/pixel over grid.x).
// Verified math (rounds 1-2, absmax 2e-3 < 9e-3): masks & 1/9 cancel in cosine;
//   V  = mym*g(y-1) + g(y) + myp*g(y+1)
//   w3 = mym*g(y)   + g(cl(y+1)) + myp*g(cl(y+2))
//   w4 = mym*g(cl(y-2)) + g(cl(y-1)) + myp*g(y)
//   f1(x) = mxm*V(cl(x-2)) + V(cl(x-1)) + mxp*V(x)
//   f2(x) = mxm*V(x) + V(cl(x+1)) + mxp*V(cl(x+2))
//   f3(x) = mxm*w3(cl(x-1)) + w3(x) + mxp*w3(cl(x+1))
//   f4(x) = mxm*w4(cl(x-1)) + w4(x) + mxp*w4(cl(x+1))
template <int CCHUNK, bool WRITE_OUT>
__global__ __launch_bounds__(256) void ComputeTotalSim_84267258347855_kernel(
    const float* __restrict__ feat, float* __restrict__ acc, float* __restrict__ out) {
    const int tid = threadIdx.x;
    const int wave = tid >> 6;
    const int lane = tid & 63;
    const int rl = lane >> 4;
    const int q = lane & 15;
    const int b = blockIdx.z;
    const int y0 = blockIdx.y * 4;
    const int y = y0 + rl;
    const int chunk = blockIdx.x * 4 + wave;

    const int x0 = q * 4;
    const int x0c = (x0 <= WW - 4) ? x0 : (WW - 4);  // load-safe for idle lanes q>=14

    const float mym = (y >= 1) ? 1.f : 0.f;
    const float myp = (y <= HH - 2) ? 1.f : 0.f;
    const float mxm[4] = {(q == 0) ? 0.f : 1.f, 1.f, 1.f, 1.f};   // (x>=1)
    const float mxp[4] = {1.f, 1.f, 1.f, (q == 13) ? 0.f : 1.f};  // (x<=54)

    const int ry0 = (y - 2 < 0) ? 0 : y - 2;
    const int ry1 = (y - 1 < 0) ? 0 : y - 1;
    const int ry2 = y;
    const int ry3 = (y + 1 > HH - 1) ? HH - 1 : y + 1;
    const int ry4 = (y + 2 > HH - 1) ? HH - 1 : y + 2;
    const int o0 = ry0 * WW + x0c, o1 = ry1 * WW + x0c, o2 = ry2 * WW + x0c,
              o3 = ry3 * WW + x0c, o4 = ry4 * WW + x0c;

    const float* p = feat + ((size_t)b * CC + (size_t)chunk * CCHUNK) * HW;

    float s12h[4] = {0, 0, 0, 0}, s11[4] = {0, 0, 0, 0}, s22[4] = {0, 0, 0, 0};
    float s12v[4] = {0, 0, 0, 0}, s33[4] = {0, 0, 0, 0}, s44[4] = {0, 0, 0, 0};

#pragma unroll 2
    for (int c = 0; c < CCHUNK; ++c, p += HW) {
        const float4 r0 = *(const float4*)(p + o0);
        const float4 r1 = *(const float4*)(p + o1);
        const float4 r2 = *(const float4*)(p + o2);
        const float4 r3 = *(const float4*)(p + o3);
        const float4 r4 = *(const float4*)(p + o4);

        float4 V, w3, w4;
        V.x = fmaf(mym, r1.x, fmaf(myp, r3.x, r2.x));
        V.y = fmaf(mym, r1.y, fmaf(myp, r3.y, r2.y));
        V.z = fmaf(mym, r1.z, fmaf(myp, r3.z, r2.z));
        V.w = fmaf(mym, r1.w, fmaf(myp, r3.w, r2.w));
        w3.x = fmaf(mym, r2.x, fmaf(myp, r4.x, r3.x));
        w3.y = fmaf(mym, r2.y, fmaf(myp, r4.y, r3.y));
        w3.z = fmaf(mym, r2.z, fmaf(myp, r4.z, r3.z));
        w3.w = fmaf(mym, r2.w, fmaf(myp, r4.w, r3.w));
        w4.x = fmaf(mym, r0.x, fmaf(myp, r2.x, r1.x));
        w4.y = fmaf(mym, r0.y, fmaf(myp, r2.y, r1.y));
        w4.z = fmaf(mym, r0.z, fmaf(myp, r2.z, r1.z));
        w4.w = fmaf(mym, r0.w, fmaf(myp, r2.w, r1.w));

        // halo from neighbor lanes (8 shuffles per 4 pixels)
        float Vm2 = shfl64(V.z, lane - 1), Vm1 = shfl64(V.w, lane - 1);
        float Vp4 = shfl64(V.x, lane + 1), Vp5 = shfl64(V.y, lane + 1);
        float w3m = shfl64(w3.w, lane - 1), w3p = shfl64(w3.x, lane + 1);
        float w4m = shfl64(w4.w, lane - 1), w4p = shfl64(w4.x, lane + 1);
        if (q == 0) { Vm2 = V.x; Vm1 = V.x; w3m = w3.x; w4m = w4.x; }   // clamp left
        if (q == 13) { Vp4 = V.w; Vp5 = V.w; w3p = w3.w; w4p = w4.w; }  // clamp right

        const float Ve[8] = {Vm2, Vm1, V.x, V.y, V.z, V.w, Vp4, Vp5};
        const float W3[6] = {w3m, w3.x, w3.y, w3.z, w3.w, w3p};
        const float W4[6] = {w4m, w4.x, w4.y, w4.z, w4.w, w4p};

#pragma unroll
        for (int i = 0; i < 4; ++i) {
            const float f1 = fmaf(mxm[i], Ve[i],     fmaf(mxp[i], Ve[i + 2], Ve[i + 1]));
            const float f2 = fmaf(mxm[i], Ve[i + 2], fmaf(mxp[i], Ve[i + 4], Ve[i + 3]));
            const float f3 = fmaf(mxm[i], W3[i],     fmaf(mxp[i], W3[i + 2], W3[i + 1]));
            const float f4 = fmaf(mxm[i], W4[i],     fmaf(mxp[i], W4[i + 2], W4[i + 1]));
            s12h[i] = fmaf(f1, f2, s12h[i]);
            s11[i]  = fmaf(f1, f1, s11[i]);
            s22[i]  = fmaf(f2, f2, s22[i]);
            s12v[i] = fmaf(f3, f4, s12v[i]);
            s33[i]  = fmaf(f3, f3, s33[i]);
            s44[i]  = fmaf(f4, f4, s44[i]);
        }
    }

    // ---- block-level reduction over the 4 waves (same 224 pixels) ----
    __shared__ float lds_acc[NVALS];
    for (int k = tid; k < NVALS; k += 256) lds_acc[k] = 0.f;
    __syncthreads();

    if (q < 14) {
        const int vbase = rl * WW + x0;
#pragma unroll
        for (int i = 0; i < 4; ++i) {
            atomicAdd(&lds_acc[0 * 224 + vbase + i], s12h[i]);
            atomicAdd(&lds_acc[1 * 224 + vbase + i], s11[i]);
            atomicAdd(&lds_acc[2 * 224 + vbase + i], s22[i]);
            atomicAdd(&lds_acc[3 * 224 + vbase + i], s12v[i]);
            atomicAdd(&lds_acc[4 * 224 + vbase + i], s33[i]);
            atomicAdd(&lds_acc[5 * 224 + vbase + i], s44[i]);
        }
    }
    __syncthreads();

    if (WRITE_OUT) {
        if (tid < 224) {
            const double a0 = lds_acc[0 * 224 + tid], a1 = lds_acc[1 * 224 + tid],
                         a2 = lds_acc[2 * 224 + tid], a3 = lds_acc[3 * 224 + tid],
                         a4 = lds_acc[4 * 224 + tid], a5 = lds_acc[5 * 224 + tid];
            out[b * HW + y0 * WW + tid] =
                (float)(0.5 * (a0 / sqrt(a1 * a2) + a3 / sqrt(a4 * a5)));
        }
    } else {
        // contiguous-address global atomics: 6 instrs/block, lane-consecutive
        const int pixbase = b * HW + y0 * WW;
        for (int k = tid; k < NVALS; k += 256) {
            const int pl = k / 224;
            const int rem = k - pl * 224;
            atomicAdd(&acc[pl * NPIX + pixbase + rem], lds_acc[k]);
        }
    }
}

__global__ void ComputeTotalSim_finalize(const float* __restrict__ acc,
                                         float* __restrict__ out) {
    const int i = blockIdx.x * blockDim.x + threadIdx.x;
    if (i < NPIX) {
        const double s12h = acc[i],            s11 = acc[NPIX + i],     s22 = acc[2 * NPIX + i];
        const double s12v = acc[3 * NPIX + i], s33 = acc[4 * NPIX + i], s44 = acc[5 * NPIX + i];
        out[i] = (float)(0.5 * (s12h / sqrt(s11 * s22) + s12v / sqrt(s33 * s44)));
    }
}

extern "C" void kernel_launch(void* const* d_in, const int* in_sizes, int n_in,
                              void* d_out, int out_size, void* d_ws, size_t ws_size,
                              hipStream_t stream) {
    const float* feat = (const float*)d_in[0];
    float* out = (float*)d_out;

    const size_t need = 6ull * NPIX * sizeof(float);
    if (ws_size >= need) {
        // Two-phase: per-block LDS reduce over 4 chunk-waves, 8 chunk-group
        // partials/pixel via coalesced atomics, then finalize.
        hipMemsetAsync(d_ws, 0, need, stream);
        dim3 grid(8, HH / 4, BB);  // 8 chunk-groups x 14 strips x 16 batches = 1792
        ComputeTotalSim_84267258347855_kernel<CC / 32, false>
            <<<grid, 256, 0, stream>>>(feat, (float*)d_ws, out);
        ComputeTotalSim_finalize<<<(NPIX + 255) / 256, 256, 0, stream>>>(
            (const float*)d_ws, out);
    } else {
        // Fallback: one block covers all channels (4 waves x 128), writes directly.
        dim3 grid(1, HH / 4, BB);
        ComputeTotalSim_84267258347855_kernel<CC / 4, true>
            <<<grid, 256, 0, stream>>>(feat, nullptr, out);
    }
}